// Round 5
// baseline (123691.577 us; speedup 1.0000x reference)
//
#include <hip/hip_runtime.h>
#include <hip/hip_cooperative_groups.h>

namespace cg = cooperative_groups;

// Problem constants
#define BB   32      // batch
#define TT_  512     // sequence length
#define DD   1024    // input dim
#define HH   1024    // hidden
#define RR_  64      // low-rank
#define FH   4096    // 4*H
#define TC   64      // timestep chunk (even => h ping-pong parity resets per chunk)

// ---------------------------------------------------------------------------
// Zero-init kernel for state buffers (ws is poisoned 0xAA before every call)
// ---------------------------------------------------------------------------
__global__ void init_zero(float4* p, int n4) {
    int i = blockIdx.x * blockDim.x + threadIdx.x;
    if (i < n4) p[i] = make_float4(0.f, 0.f, 0.f, 0.f);
}

// ---------------------------------------------------------------------------
// fp32 tiled GEMM: C[m][n] = sum_k Arow(m)[k] * W[n][k] + bias[n]
// Row m decomposes as m = tt*32 + b ; rowptr = Abase + tt*strideT + b*strideB
// ---------------------------------------------------------------------------
template<int BM, int BN, int BK, int TM, int TN>
__global__ __launch_bounds__(256) void gemm_xw(
    const float* __restrict__ Abase, long strideT, long strideB,
    const float* __restrict__ W, const float* __restrict__ bias,
    float* __restrict__ C, int M, int N, int K)
{
    constexpr int NT = (BM / TM) * (BN / TN);
    static_assert(NT == 256, "256 threads");
    __shared__ float As[BK][BM];
    __shared__ float Bs[BK][BN];
    const int tid = threadIdx.x;
    const long bm = (long)blockIdx.y * BM;
    const long bn = (long)blockIdx.x * BN;
    constexpr int TX = BN / TN;
    const int tx = tid % TX, ty = tid / TX;
    float acc[TM][TN] = {};

    for (int k0 = 0; k0 < K; k0 += BK) {
        for (int i = tid; i < BM * (BK / 4); i += NT) {
            int r = i / (BK / 4), kc = (i % (BK / 4)) * 4;
            long m = bm + r;
            const float* Ar = Abase + (m >> 5) * strideT + (m & 31) * strideB + k0 + kc;
            float4 v = *(const float4*)Ar;
            As[kc + 0][r] = v.x; As[kc + 1][r] = v.y;
            As[kc + 2][r] = v.z; As[kc + 3][r] = v.w;
        }
        for (int i = tid; i < BN * (BK / 4); i += NT) {
            int r = i / (BK / 4), kc = (i % (BK / 4)) * 4;
            float4 v = *(const float4*)(W + (bn + r) * (long)K + k0 + kc);
            Bs[kc + 0][r] = v.x; Bs[kc + 1][r] = v.y;
            Bs[kc + 2][r] = v.z; Bs[kc + 3][r] = v.w;
        }
        __syncthreads();
#pragma unroll
        for (int kk = 0; kk < BK; ++kk) {
            float a[TM], bv[TN];
#pragma unroll
            for (int i2 = 0; i2 < TM; ++i2) a[i2] = As[kk][ty * TM + i2];
#pragma unroll
            for (int j2 = 0; j2 < TN; ++j2) bv[j2] = Bs[kk][tx * TN + j2];
#pragma unroll
            for (int i2 = 0; i2 < TM; ++i2)
#pragma unroll
                for (int j2 = 0; j2 < TN; ++j2)
                    acc[i2][j2] += a[i2] * bv[j2];
        }
        __syncthreads();
    }
#pragma unroll
    for (int i2 = 0; i2 < TM; ++i2) {
        long m = bm + ty * TM + i2;
#pragma unroll
        for (int j2 = 0; j2 < TN; ++j2) {
            long n = bn + tx * TN + j2;
            float v = acc[i2][j2];
            if (bias) v += bias[n];
            C[m * N + n] = v;
        }
    }
}

// ---------------------------------------------------------------------------
// Persistent cooperative sLSTM scan: runs `nsteps` timesteps with grid.sync()
// between steps. Grid: 256 blocks x 256 threads (1 block/CU).
// Block owns 4 j-columns (16 U rows over 4 gates) x all 32 batches.
// h in transposed layout: float4 index d4*32+b holds h[b][4*d4..+3].
// ---------------------------------------------------------------------------
__global__ __launch_bounds__(256) void slstm_scan(
    const float* __restrict__ xw0,   // [TC][B][4H]
    const float* __restrict__ U,     // [4H][H]
    const float* __restrict__ bU,    // [4H]
    const float* __restrict__ alpha, // [H]
    float* __restrict__ h0buf, float* __restrict__ h1buf,  // hT layout
    float* __restrict__ cst,         // [B][H]
    float* __restrict__ out1c,       // [TC][B][H]
    int nsteps)
{
    cg::grid_group grid = cg::this_grid();
    __shared__ float4 hs[2048];      // 32 KB: quarter of h
    __shared__ float  zs[16][32];
    const int tid = threadIdx.x;
    const int b = tid & 31, rr = tid >> 5;      // rr 0..7
    const int j0 = blockIdx.x * 4;
    const int g0 = rr >> 2, jj0 = rr & 3;
    const float4* U0 = (const float4*)(U + (long)(g0 * HH + j0 + jj0) * HH);
    const float4* U1 = (const float4*)(U + (long)((g0 + 2) * HH + j0 + jj0) * HH);

    for (int tt = 0; tt < nsteps; ++tt) {
        const float4* hin4 = (const float4*)((tt & 1) ? h1buf : h0buf);
        float* hout        = (tt & 1) ? h0buf : h1buf;
        const float* xw    = xw0 + (long)tt * BB * FH;

        float p0[4] = {0.f,0.f,0.f,0.f}, p1[4] = {0.f,0.f,0.f,0.f};
        for (int ph = 0; ph < 4; ++ph) {
            const int base = ph * 2048;
            for (int i = tid; i < 2048; i += 256) hs[i] = hin4[base + i];
            __syncthreads();
#pragma unroll 8
            for (int dd = 0; dd < 64; ++dd) {
                const int d4 = ph * 64 + dd;
                const int sl = dd & 3;
                float4 hv = hs[dd * 32 + b];
                float4 u0 = U0[d4];
                float4 u1 = U1[d4];
                p0[sl] += u0.x*hv.x + u0.y*hv.y + u0.z*hv.z + u0.w*hv.w;
                p1[sl] += u1.x*hv.x + u1.y*hv.y + u1.z*hv.z + u1.w*hv.w;
            }
            __syncthreads();
        }
        zs[rr][b]     = (p0[0]+p0[1]) + (p0[2]+p0[3]);
        zs[rr + 8][b] = (p1[0]+p1[1]) + (p1[2]+p1[3]);
        __syncthreads();

        if (tid < 128) {
            const int b2 = tid & 31, jj = tid >> 5;  // jj 0..3
            const int j = j0 + jj;
            const long xb = (long)b2 * FH;
            float zi = xw[xb + j]            + zs[jj][b2]      + bU[j];
            float zf = xw[xb + HH + j]       + zs[4 + jj][b2]  + bU[HH + j];
            float zo = xw[xb + 2 * HH + j]   + zs[8 + jj][b2]  + bU[2 * HH + j];
            float zg = xw[xb + 3 * HH + j]   + zs[12 + jj][b2] + bU[3 * HH + j];
            float ig = 1.f / (1.f + expf(-zi));
            float fg = 1.f / (1.f + expf(-zf));
            float og = 1.f / (1.f + expf(-zo));
            float g  = tanhf(zg);
            float cold = cst[b2 * HH + j];
            float cn = alpha[j] * (fg * cold + ig * g);
            float hn = og * tanhf(cn);
            cst[b2 * HH + j] = cn;
            hout[((long)blockIdx.x * 32 + b2) * 4 + jj] = hn;
            out1c[(long)tt * BB * HH + (long)b2 * HH + j] = hn;
        }
        __threadfence();
        grid.sync();
    }
}

// ---------------------------------------------------------------------------
// Persistent cooperative mLSTM scan. Adds per-step q = xa ⊙ (h@Bm.T) phase
// (each block computes 8 of the 2048 q entries) + low-rank mix epilogue.
// Two grid.sync() per step: (zs,q ready) and (h_t ready).
// ---------------------------------------------------------------------------
__global__ __launch_bounds__(256) void mlstm_scan(
    const float* __restrict__ xw0,   // [TC][B][4H]
    const float* __restrict__ U,     // Um [4H][H]
    const float* __restrict__ bU,    // [4H]
    const float* __restrict__ Bm,    // [R][H]
    const float* __restrict__ P,     // [H][R]
    const float* __restrict__ xa0,   // [TC][B][R]
    float* __restrict__ h0buf, float* __restrict__ h1buf,
    float* __restrict__ cst,
    float* __restrict__ qbuf,        // [B][R]
    float* __restrict__ out,         // [B][T][H] fp32
    int t0, int nsteps)
{
    cg::grid_group grid = cg::this_grid();
    __shared__ float4 hs[2048];
    __shared__ float  zs[16][32];
    const int tid = threadIdx.x;
    const int b = tid & 31, rr = tid >> 5;
    const int j0 = blockIdx.x * 4;
    const int g0 = rr >> 2, jj0 = rr & 3;
    const float4* U0 = (const float4*)(U + (long)(g0 * HH + j0 + jj0) * HH);
    const float4* U1 = (const float4*)(U + (long)((g0 + 2) * HH + j0 + jj0) * HH);

    for (int tt = 0; tt < nsteps; ++tt) {
        const float4* hin4 = (const float4*)((tt & 1) ? h1buf : h0buf);
        float* hout        = (tt & 1) ? h0buf : h1buf;
        const float* xw    = xw0 + (long)tt * BB * FH;

        float p0[4] = {0.f,0.f,0.f,0.f}, p1[4] = {0.f,0.f,0.f,0.f};
        for (int ph = 0; ph < 4; ++ph) {
            const int base = ph * 2048;
            for (int i = tid; i < 2048; i += 256) hs[i] = hin4[base + i];
            __syncthreads();
#pragma unroll 8
            for (int dd = 0; dd < 64; ++dd) {
                const int d4 = ph * 64 + dd;
                const int sl = dd & 3;
                float4 hv = hs[dd * 32 + b];
                float4 u0 = U0[d4];
                float4 u1 = U1[d4];
                p0[sl] += u0.x*hv.x + u0.y*hv.y + u0.z*hv.z + u0.w*hv.w;
                p1[sl] += u1.x*hv.x + u1.y*hv.y + u1.z*hv.z + u1.w*hv.w;
            }
            __syncthreads();
        }
        zs[rr][b]     = (p0[0]+p0[1]) + (p0[2]+p0[3]);
        zs[rr + 8][b] = (p1[0]+p1[1]) + (p1[2]+p1[3]);

        // ---- q phase: block computes entries idx = blockIdx.x*8 .. +7 ----
        if (tid < 64) {
            const int e = tid >> 3, sub = tid & 7;
            const int idx = blockIdx.x * 8 + e;
            const int qb = idx >> 6, qr = idx & 63;
            const float4* bm4 = (const float4*)(Bm + (long)qr * HH);
            float acc = 0.f;
#pragma unroll 4
            for (int i = 0; i < 32; ++i) {
                const int k4 = sub + (i << 3);
                float4 hv = hin4[k4 * 32 + qb];
                float4 bv = bm4[k4];
                acc += hv.x*bv.x + hv.y*bv.y + hv.z*bv.z + hv.w*bv.w;
            }
            acc += __shfl_down(acc, 4, 64);
            acc += __shfl_down(acc, 2, 64);
            acc += __shfl_down(acc, 1, 64);
            if (sub == 0)
                qbuf[idx] = acc * xa0[(long)tt * BB * RR_ + idx];
        }
        __threadfence();
        grid.sync();    // zs visible in-block (implies block sync), q visible grid-wide

        if (tid < 128) {
            const int b2 = tid & 31, jj = tid >> 5;
            const int j = j0 + jj;
            const long xb = (long)b2 * FH;
            float zi = xw[xb + j]          + zs[jj][b2]      + bU[j];
            float zf = xw[xb + HH + j]     + zs[4 + jj][b2]  + bU[HH + j];
            float zo = xw[xb + 2 * HH + j] + zs[8 + jj][b2]  + bU[2 * HH + j];
            float zg = xw[xb + 3 * HH + j] + zs[12 + jj][b2] + bU[3 * HH + j];
            float ig = 1.f / (1.f + expf(-zi));
            float fg = 1.f / (1.f + expf(-zf));
            float og = 1.f / (1.f + expf(-zo));
            float g  = tanhf(zg);
            float mx = 0.f;
            const float4* Pj = (const float4*)(P + (long)j * RR_);
            const float4* qb4 = (const float4*)(qbuf + (long)b2 * RR_);
#pragma unroll
            for (int r4 = 0; r4 < 16; ++r4) {
                float4 pv = Pj[r4], qv = qb4[r4];
                mx += pv.x*qv.x + pv.y*qv.y + pv.z*qv.z + pv.w*qv.w;
            }
            float cold = cst[b2 * HH + j];
            float cn = fg * cold + ig * g + 0.1f * mx;
            float hn = og * tanhf(cn);
            cst[b2 * HH + j] = cn;
            hout[((long)blockIdx.x * 32 + b2) * 4 + jj] = hn;
            out[(long)b2 * (TT_ * HH) + (long)(t0 + tt) * HH + j] = hn;
        }
        __threadfence();
        grid.sync();
    }
}

// ---------------------------------------------------------------------------
// Launch: per 64-step chunk: gemm_s -> coop sLSTM scan -> gemm_m + gemm_xa ->
// coop mLSTM scan. 41 dispatches total (vs 1585 in round 4).
// Workspace ~41.5 MB fp32.
// ---------------------------------------------------------------------------
extern "C" void kernel_launch(void* const* d_in, const int* in_sizes, int n_in,
                              void* d_out, int out_size, void* d_ws, size_t ws_size,
                              hipStream_t stream) {
    const float* x     = (const float*)d_in[0];
    const float* Ws    = (const float*)d_in[1];
    const float* bWs   = (const float*)d_in[2];
    const float* Us    = (const float*)d_in[3];
    const float* bUs   = (const float*)d_in[4];
    const float* alpha = (const float*)d_in[5];
    const float* Wm    = (const float*)d_in[6];
    const float* bWm   = (const float*)d_in[7];
    const float* Um    = (const float*)d_in[8];
    const float* bUm   = (const float*)d_in[9];
    const float* A     = (const float*)d_in[10];
    const float* Bm    = (const float*)d_in[11];
    const float* P     = (const float*)d_in[12];
    float* out = (float*)d_out;

    float* w      = (float*)d_ws;
    float* xwbuf  = w;                               // TC*B*4H = 8,388,608 f (32 MB)
    float* out1c  = xwbuf + (long)TC * BB * FH;      // TC*B*H  = 2,097,152 f (8 MB)
    float* xac    = out1c + (long)TC * BB * HH;      // TC*B*R  = 131,072 f (512 KB)
    float* hA     = xac + (long)TC * BB * RR_;       // states: 32768 f each
    float* hB     = hA + BB * HH;
    float* cS     = hB + BB * HH;
    float* hmA    = cS + BB * HH;
    float* hmB    = hmA + BB * HH;
    float* cM     = hmB + BB * HH;
    float* q      = cM + BB * HH;                    // 2048 f

    // zero state buffers (hA..q): 6*32768 + 2048 = 198656 floats = 49664 float4
    init_zero<<<194, 256, 0, stream>>>((float4*)hA, 49664);

    dim3 gbig(FH / 64, (TC * BB) / 64);   // (64, 32) = 2048 blocks
    dim3 gxa(RR_ / 64, (TC * BB) / 64);   // (1, 32)
    int nsteps = TC;

    for (int ch = 0; ch < TT_ / TC; ++ch) {
        int t0 = ch * TC;

        // ---- sLSTM: xw = x_chunk @ Ws.T + bWs ----
        gemm_xw<64, 64, 16, 4, 4><<<gbig, 256, 0, stream>>>(
            x + (long)t0 * DD, (long)DD, (long)TT_ * DD, Ws, bWs,
            xwbuf, TC * BB, FH, DD);

        {
            void* args[] = {
                (void*)&xwbuf, (void*)&Us, (void*)&bUs, (void*)&alpha,
                (void*)&hA, (void*)&hB, (void*)&cS, (void*)&out1c, (void*)&nsteps
            };
            hipLaunchCooperativeKernel((const void*)slstm_scan,
                dim3(256), dim3(256), args, 0, stream);
        }

        // ---- mLSTM projections (xwbuf reuse is stream-ordered safe) ----
        gemm_xw<64, 64, 16, 4, 4><<<gbig, 256, 0, stream>>>(
            out1c, (long)BB * HH, (long)HH, Wm, bWm,
            xwbuf, TC * BB, FH, HH);
        gemm_xw<64, 64, 16, 4, 4><<<gxa, 256, 0, stream>>>(
            out1c, (long)BB * HH, (long)HH, A, nullptr,
            xac, TC * BB, RR_, HH);

        {
            void* args[] = {
                (void*)&xwbuf, (void*)&Um, (void*)&bUm, (void*)&Bm, (void*)&P,
                (void*)&xac, (void*)&hmA, (void*)&hmB, (void*)&cM, (void*)&q,
                (void*)&out, (void*)&t0, (void*)&nsteps
            };
            hipLaunchCooperativeKernel((const void*)mlstm_scan,
                dim3(256), dim3(256), args, 0, stream);
        }
    }
}

// Round 6
// 56920.819 us; speedup vs baseline: 2.1730x; 2.1730x over previous
//
#include <hip/hip_runtime.h>

// Problem constants
#define BB   32      // batch
#define TT_  512     // sequence length
#define DD   1024    // input dim
#define HH   1024    // hidden
#define RR_  64      // low-rank
#define FH   4096    // 4*H
#define TC   32      // timestep chunk
#define NCH  (TT_ / TC)   // 16 chunks

// ---------------------------------------------------------------------------
// Zero-init for state buffers (ws poisoned 0xAA before every call)
// ---------------------------------------------------------------------------
__global__ void init_zero(float4* p, int n4) {
    int i = blockIdx.x * blockDim.x + threadIdx.x;
    if (i < n4) p[i] = make_float4(0.f, 0.f, 0.f, 0.f);
}

// ---------------------------------------------------------------------------
// fp32 tiled GEMM: C[m][n] = sum_k Arow(m)[k] * W[n][k] + bias[n]
// Row m = tt*32 + b ; rowptr = Abase + tt*strideT + b*strideB
// 128x128x16 (or 128x64) tiles, TMxTN per thread, 256 threads.
// ---------------------------------------------------------------------------
template<int BM, int BN, int BK, int TM, int TN>
__global__ __launch_bounds__(256) void gemm_xw(
    const float* __restrict__ Abase, long strideT, long strideB,
    const float* __restrict__ W, const float* __restrict__ bias,
    float* __restrict__ C, int N, int K)
{
    constexpr int NT = (BM / TM) * (BN / TN);
    static_assert(NT == 256, "256 threads");
    __shared__ float As[BK][BM];
    __shared__ float Bs[BK][BN];
    const int tid = threadIdx.x;
    const long bm = (long)blockIdx.y * BM;
    const long bn = (long)blockIdx.x * BN;
    constexpr int TX = BN / TN;
    const int tx = tid % TX, ty = tid / TX;
    float acc[TM][TN] = {};

    for (int k0 = 0; k0 < K; k0 += BK) {
#pragma unroll
        for (int i0 = 0; i0 < BM * (BK / 4); i0 += NT) {
            int i = i0 + tid;
            int r = i / (BK / 4), kc = (i % (BK / 4)) * 4;
            long m = bm + r;
            const float* Ar = Abase + (m >> 5) * strideT + (m & 31) * strideB + k0 + kc;
            float4 v = *(const float4*)Ar;
            As[kc + 0][r] = v.x; As[kc + 1][r] = v.y;
            As[kc + 2][r] = v.z; As[kc + 3][r] = v.w;
        }
#pragma unroll
        for (int i0 = 0; i0 < BN * (BK / 4); i0 += NT) {
            int i = i0 + tid;
            int r = i / (BK / 4), kc = (i % (BK / 4)) * 4;
            float4 v = *(const float4*)(W + (bn + r) * (long)K + k0 + kc);
            Bs[kc + 0][r] = v.x; Bs[kc + 1][r] = v.y;
            Bs[kc + 2][r] = v.z; Bs[kc + 3][r] = v.w;
        }
        __syncthreads();
#pragma unroll
        for (int kk = 0; kk < BK; ++kk) {
            float a[TM], bv[TN];
#pragma unroll
            for (int i2 = 0; i2 < TM; ++i2) a[i2] = As[kk][ty * TM + i2];
#pragma unroll
            for (int j2 = 0; j2 < TN; ++j2) bv[j2] = Bs[kk][tx * TN + j2];
#pragma unroll
            for (int i2 = 0; i2 < TM; ++i2)
#pragma unroll
                for (int j2 = 0; j2 < TN; ++j2)
                    acc[i2][j2] += a[i2] * bv[j2];
        }
        __syncthreads();
    }
#pragma unroll
    for (int i2 = 0; i2 < TM; ++i2) {
        long m = bm + ty * TM + i2;
#pragma unroll
        for (int j2 = 0; j2 < TN; ++j2) {
            long n = bn + tx * TN + j2;
            float v = acc[i2][j2];
            if (bias) v += bias[n];
            C[m * N + n] = v;
        }
    }
}

// ---------------------------------------------------------------------------
// Fused D1 dispatch: blocks [0, s_blocks) run one sLSTM step (chunk c+1);
// blocks [s_blocks, s_blocks+32) compute mLSTM q for chunk c's current step
// (q_t = xa_t ⊙ (h^m_{t-1} @ Bm.T); h^m_{t-1} is global-visible at start).
// h layout (both nets): float4 index d4*32+b holds h[b][4*d4..+3].
// ---------------------------------------------------------------------------
__global__ __launch_bounds__(256) void step_fused(
    const float* __restrict__ xwS,   // xwS + tt*B*4H  [b][4H]
    const float* __restrict__ Us,    // [4H][H]
    const float* __restrict__ bUs,   // [4H]
    const float* __restrict__ alpha, // [H]
    const float* __restrict__ hinS,  // hT layout
    float* __restrict__ houtS,
    float* __restrict__ cS,          // [B][H]
    float* __restrict__ out1t,       // out1buf + tt*B*H  [b][H]
    const float* __restrict__ hinM,  // mLSTM h_{t-1}, hT layout
    const float* __restrict__ Bm,    // [R][H]
    const float* __restrict__ xat,   // xac + tt*B*R  [b][R]
    float* __restrict__ qout,        // [B][R]
    int s_blocks)
{
    __shared__ float4 hs[2048];      // 32 KB (slstm role)
    __shared__ float  zs[16][32];
    const int tid = threadIdx.x;

    if ((int)blockIdx.x >= s_blocks) {
        // ---- q role: block k handles batch b=k, all 64 r ----
        const int k = blockIdx.x - s_blocks;
        const int e = tid >> 2, sub = tid & 3;   // r, k-slice
        const float4* h4 = (const float4*)hinM;
        const float4* bm4 = (const float4*)(Bm + (long)e * HH);
        float acc = 0.f;
#pragma unroll 8
        for (int i = 0; i < 64; ++i) {
            const int k4 = sub * 64 + i;
            float4 hv = h4[k4 * 32 + k];
            float4 bv = bm4[k4];
            acc += hv.x*bv.x + hv.y*bv.y + hv.z*bv.z + hv.w*bv.w;
        }
        acc += __shfl_down(acc, 2, 4);
        acc += __shfl_down(acc, 1, 4);
        if (sub == 0) qout[k * RR_ + e] = acc * xat[k * RR_ + e];
        return;
    }

    // ---- sLSTM role ----
    const int b = tid & 31, rr = tid >> 5;      // rr 0..7
    const int j0 = blockIdx.x * 4;
    const int g0 = rr >> 2, jj0 = rr & 3;
    const float4* hin4 = (const float4*)hinS;
    const float4* U0 = (const float4*)(Us + (long)(g0 * HH + j0 + jj0) * HH);
    const float4* U1 = (const float4*)(Us + (long)((g0 + 2) * HH + j0 + jj0) * HH);

    float p0[4] = {0.f,0.f,0.f,0.f}, p1[4] = {0.f,0.f,0.f,0.f};
    for (int ph = 0; ph < 4; ++ph) {
        const int base = ph * 2048;
        for (int i = tid; i < 2048; i += 256) hs[i] = hin4[base + i];
        __syncthreads();
#pragma unroll 8
        for (int dd = 0; dd < 64; ++dd) {
            const int d4 = ph * 64 + dd;
            const int sl = dd & 3;
            float4 hv = hs[dd * 32 + b];
            float4 u0 = U0[d4];
            float4 u1 = U1[d4];
            p0[sl] += u0.x*hv.x + u0.y*hv.y + u0.z*hv.z + u0.w*hv.w;
            p1[sl] += u1.x*hv.x + u1.y*hv.y + u1.z*hv.z + u1.w*hv.w;
        }
        __syncthreads();
    }
    zs[rr][b]     = (p0[0]+p0[1]) + (p0[2]+p0[3]);
    zs[rr + 8][b] = (p1[0]+p1[1]) + (p1[2]+p1[3]);
    __syncthreads();

    if (tid < 32) {
        const int b2 = tid;
        const long xb = (long)b2 * FH;
        float4 zi4 = *(const float4*)(xwS + xb + j0);
        float4 zf4 = *(const float4*)(xwS + xb + HH + j0);
        float4 zo4 = *(const float4*)(xwS + xb + 2 * HH + j0);
        float4 zg4 = *(const float4*)(xwS + xb + 3 * HH + j0);
        float4 bi4 = *(const float4*)(bUs + j0);
        float4 bf4 = *(const float4*)(bUs + HH + j0);
        float4 bo4 = *(const float4*)(bUs + 2 * HH + j0);
        float4 bg4 = *(const float4*)(bUs + 3 * HH + j0);
        float4 al4 = *(const float4*)(alpha + j0);
        float4 c4  = *(const float4*)(cS + (long)b2 * HH + j0);
        const float* zi = (const float*)&zi4; const float* zf = (const float*)&zf4;
        const float* zo = (const float*)&zo4; const float* zg = (const float*)&zg4;
        const float* bi = (const float*)&bi4; const float* bf = (const float*)&bf4;
        const float* bo = (const float*)&bo4; const float* bg = (const float*)&bg4;
        const float* al = (const float*)&al4; float* cp = (float*)&c4;
        float4 hn4; float* hn = (float*)&hn4;
#pragma unroll
        for (int jj = 0; jj < 4; ++jj) {
            float vi = zi[jj] + zs[jj][b2]      + bi[jj];
            float vf = zf[jj] + zs[4 + jj][b2]  + bf[jj];
            float vo = zo[jj] + zs[8 + jj][b2]  + bo[jj];
            float vg = zg[jj] + zs[12 + jj][b2] + bg[jj];
            float ig = 1.f / (1.f + expf(-vi));
            float fg = 1.f / (1.f + expf(-vf));
            float og = 1.f / (1.f + expf(-vo));
            float g  = tanhf(vg);
            float cn = al[jj] * (fg * cp[jj] + ig * g);
            cp[jj] = cn;
            hn[jj] = og * tanhf(cn);
        }
        *(float4*)(cS + (long)b2 * HH + j0) = c4;
        ((float4*)houtS)[(long)blockIdx.x * 32 + b2] = hn4;
        *(float4*)(out1t + (long)b2 * HH + j0) = hn4;
    }
}

// ---------------------------------------------------------------------------
// D2: mLSTM step (q already computed by the preceding fused dispatch).
// ---------------------------------------------------------------------------
__global__ __launch_bounds__(256) void mlstm_step(
    const float* __restrict__ xw,    // xwM + tt*B*4H
    const float* __restrict__ U,     // Um [4H][H]
    const float* __restrict__ bU,    // [4H]
    const float* __restrict__ P,     // [H][R]
    const float* __restrict__ q,     // [B][R]
    const float* __restrict__ hin,   // hT layout
    float* __restrict__ hout,
    float* __restrict__ cst,         // [B][H]
    float* __restrict__ out,         // [B][T][H] fp32
    int t)
{
    __shared__ float4 hs[2048];
    __shared__ float  zs[16][32];
    const int tid = threadIdx.x;
    const int b = tid & 31, rr = tid >> 5;
    const int j0 = blockIdx.x * 4;
    const int g0 = rr >> 2, jj0 = rr & 3;
    const float4* hin4 = (const float4*)hin;
    const float4* U0 = (const float4*)(U + (long)(g0 * HH + j0 + jj0) * HH);
    const float4* U1 = (const float4*)(U + (long)((g0 + 2) * HH + j0 + jj0) * HH);

    float p0[4] = {0.f,0.f,0.f,0.f}, p1[4] = {0.f,0.f,0.f,0.f};
    for (int ph = 0; ph < 4; ++ph) {
        const int base = ph * 2048;
        for (int i = tid; i < 2048; i += 256) hs[i] = hin4[base + i];
        __syncthreads();
#pragma unroll 8
        for (int dd = 0; dd < 64; ++dd) {
            const int d4 = ph * 64 + dd;
            const int sl = dd & 3;
            float4 hv = hs[dd * 32 + b];
            float4 u0 = U0[d4];
            float4 u1 = U1[d4];
            p0[sl] += u0.x*hv.x + u0.y*hv.y + u0.z*hv.z + u0.w*hv.w;
            p1[sl] += u1.x*hv.x + u1.y*hv.y + u1.z*hv.z + u1.w*hv.w;
        }
        __syncthreads();
    }
    zs[rr][b]     = (p0[0]+p0[1]) + (p0[2]+p0[3]);
    zs[rr + 8][b] = (p1[0]+p1[1]) + (p1[2]+p1[3]);
    __syncthreads();

    if (tid < 32) {
        const int b2 = tid;
        const long xb = (long)b2 * FH;
        float4 zi4 = *(const float4*)(xw + xb + j0);
        float4 zf4 = *(const float4*)(xw + xb + HH + j0);
        float4 zo4 = *(const float4*)(xw + xb + 2 * HH + j0);
        float4 zg4 = *(const float4*)(xw + xb + 3 * HH + j0);
        float4 bi4 = *(const float4*)(bU + j0);
        float4 bf4 = *(const float4*)(bU + HH + j0);
        float4 bo4 = *(const float4*)(bU + 2 * HH + j0);
        float4 bg4 = *(const float4*)(bU + 3 * HH + j0);
        float4 c4  = *(const float4*)(cst + (long)b2 * HH + j0);
        const float* zi = (const float*)&zi4; const float* zf = (const float*)&zf4;
        const float* zo = (const float*)&zo4; const float* zg = (const float*)&zg4;
        const float* bi = (const float*)&bi4; const float* bf = (const float*)&bf4;
        const float* bo = (const float*)&bo4; const float* bg = (const float*)&bg4;
        float* cp = (float*)&c4;
        // mix[jj] = sum_r q[b2][r] * P[j0+jj][r]
        float mx[4] = {0.f, 0.f, 0.f, 0.f};
        const float4* qb4 = (const float4*)(q + (long)b2 * RR_);
        const float4* P0 = (const float4*)(P + (long)(j0 + 0) * RR_);
        const float4* P1 = (const float4*)(P + (long)(j0 + 1) * RR_);
        const float4* P2 = (const float4*)(P + (long)(j0 + 2) * RR_);
        const float4* P3 = (const float4*)(P + (long)(j0 + 3) * RR_);
#pragma unroll
        for (int r4 = 0; r4 < 16; ++r4) {
            float4 qv = qb4[r4];
            float4 v0 = P0[r4], v1 = P1[r4], v2 = P2[r4], v3 = P3[r4];
            mx[0] += v0.x*qv.x + v0.y*qv.y + v0.z*qv.z + v0.w*qv.w;
            mx[1] += v1.x*qv.x + v1.y*qv.y + v1.z*qv.z + v1.w*qv.w;
            mx[2] += v2.x*qv.x + v2.y*qv.y + v2.z*qv.z + v2.w*qv.w;
            mx[3] += v3.x*qv.x + v3.y*qv.y + v3.z*qv.z + v3.w*qv.w;
        }
        float4 hn4; float* hn = (float*)&hn4;
#pragma unroll
        for (int jj = 0; jj < 4; ++jj) {
            float vi = zi[jj] + zs[jj][b2]      + bi[jj];
            float vf = zf[jj] + zs[4 + jj][b2]  + bf[jj];
            float vo = zo[jj] + zs[8 + jj][b2]  + bo[jj];
            float vg = zg[jj] + zs[12 + jj][b2] + bg[jj];
            float ig = 1.f / (1.f + expf(-vi));
            float fg = 1.f / (1.f + expf(-vf));
            float og = 1.f / (1.f + expf(-vo));
            float g  = tanhf(vg);
            float cn = fg * cp[jj] + ig * g + 0.1f * mx[jj];
            cp[jj] = cn;
            hn[jj] = og * tanhf(cn);
        }
        *(float4*)(cst + (long)b2 * HH + j0) = c4;
        ((float4*)hout)[(long)blockIdx.x * 32 + b2] = hn4;
        *(float4*)(out + (long)b2 * (TT_ * HH) + (long)t * HH + j0) = hn4;
    }
}

// ---------------------------------------------------------------------------
// Launch: software-pipelined chunks. Steady state per step: ONE fused dispatch
// (sLSTM step of chunk c+1 + q of chunk c) + ONE mLSTM dispatch. 1105 total.
// Workspace ~41.0 MB fp32.
// ---------------------------------------------------------------------------
extern "C" void kernel_launch(void* const* d_in, const int* in_sizes, int n_in,
                              void* d_out, int out_size, void* d_ws, size_t ws_size,
                              hipStream_t stream) {
    const float* x     = (const float*)d_in[0];
    const float* Ws    = (const float*)d_in[1];
    const float* bWs   = (const float*)d_in[2];
    const float* Us    = (const float*)d_in[3];
    const float* bUs   = (const float*)d_in[4];
    const float* alpha = (const float*)d_in[5];
    const float* Wm    = (const float*)d_in[6];
    const float* bWm   = (const float*)d_in[7];
    const float* Um    = (const float*)d_in[8];
    const float* bUm   = (const float*)d_in[9];
    const float* A     = (const float*)d_in[10];
    const float* Bm    = (const float*)d_in[11];
    const float* P     = (const float*)d_in[12];
    float* out = (float*)d_out;

    float* w     = (float*)d_ws;
    float* xwS   = w;                                // TC*B*4H = 4,194,304 f
    float* xwM   = xwS + (long)TC * BB * FH;         // 4,194,304 f
    float* out1A = xwM + (long)TC * BB * FH;         // TC*B*H = 1,048,576 f
    float* out1B = out1A + (long)TC * BB * HH;       // 1,048,576 f
    float* xac   = out1B + (long)TC * BB * HH;       // TC*B*R = 65,536 f
    float* hA    = xac + (long)TC * BB * RR_;        // states: 32768 f each
    float* hB    = hA + BB * HH;
    float* cS    = hB + BB * HH;
    float* hmA   = cS + BB * HH;
    float* hmB   = hmA + BB * HH;
    float* cM    = hmB + BB * HH;
    float* q     = cM + BB * HH;                     // 2048 f
    // total ≈ 41.0 MB

    init_zero<<<194, 256, 0, stream>>>((float4*)hA, 49664);

    dim3 gbig(FH / 128, (TC * BB) / 128);   // (32, 8) = 256 blocks
    dim3 gxa(RR_ / 64, (TC * BB) / 128);    // (1, 8)  = 8 blocks

    // ---- prologue: xwS(chunk 0) + sLSTM chunk 0 ----
    gemm_xw<128, 128, 16, 8, 8><<<gbig, 256, 0, stream>>>(
        x, (long)DD, (long)TT_ * DD, Ws, bWs, xwS, FH, DD);
    for (int tt = 0; tt < TC; ++tt) {
        const int ts = tt;
        const float* hin = (ts & 1) ? hB : hA;
        float* hout      = (ts & 1) ? hA : hB;
        step_fused<<<256, 256, 0, stream>>>(
            xwS + (long)tt * BB * FH, Us, bUs, alpha,
            hin, hout, cS, out1A + (long)tt * BB * HH,
            hmA, Bm, xac, q, 256);
    }

    // ---- main pipeline over mLSTM chunks c = 0..15 ----
    for (int c = 0; c < NCH; ++c) {
        float* out1cur = (c & 1) ? out1B : out1A;   // sLSTM chunk c output
        float* out1nxt = (c & 1) ? out1A : out1B;   // sLSTM chunk c+1 target

        gemm_xw<128, 128, 16, 8, 8><<<gbig, 256, 0, stream>>>(
            out1cur, (long)BB * HH, (long)HH, Wm, bWm, xwM, FH, HH);
        gemm_xw<128, 64, 16, 8, 4><<<gxa, 256, 0, stream>>>(
            out1cur, (long)BB * HH, (long)HH, A, nullptr, xac, RR_, HH);
        if (c < NCH - 1) {
            gemm_xw<128, 128, 16, 8, 8><<<gbig, 256, 0, stream>>>(
                x + (long)(c + 1) * TC * DD, (long)DD, (long)TT_ * DD,
                Ws, bWs, xwS, FH, DD);
        }

        const int s_blocks = (c < NCH - 1) ? 256 : 0;
        for (int tt = 0; tt < TC; ++tt) {
            const int ts = (c + 1) * TC + tt;   // sLSTM global step
            const int tm = c * TC + tt;         // mLSTM global step
            const float* hinS = (ts & 1) ? hB : hA;
            float* houtS      = (ts & 1) ? hA : hB;
            const float* hinM = (tm & 1) ? hmB : hmA;
            float* houtM      = (tm & 1) ? hmA : hmB;

            step_fused<<<s_blocks + 32, 256, 0, stream>>>(
                xwS + (long)tt * BB * FH, Us, bUs, alpha,
                hinS, houtS, cS, out1nxt + (long)tt * BB * HH,
                hinM, Bm, xac + (long)tt * BB * RR_, q, s_blocks);

            mlstm_step<<<256, 256, 0, stream>>>(
                xwM + (long)tt * BB * FH, Um, bUm, P, q,
                hinM, houtM, cM, out, tm);
        }
    }
}